// Round 13
// baseline (225.438 us; speedup 1.0000x reference)
//
#include <hip/hip_runtime.h>

#define NN   100000
#define NE   1600000
#define DIN  128
#define DH   64
#define DOUT 128
#define NG   512

#define NB    391    // dst buckets of 256 nodes: ceil(NN/256)
#define PARTB 250    // partA blocks
#define EPB   6400   // edges per partA block (= NE/250; 16B-aligned slices)
#define CAP   5120   // padded bucket capacity (verified sufficient rounds 8-12)

typedef short short8 __attribute__((ext_vector_type(8)));
typedef float floatx4 __attribute__((ext_vector_type(4)));

__device__ __forceinline__ unsigned short f2bf(float f) {
  unsigned b = __float_as_uint(f);
  b += 0x7FFF + ((b >> 16) & 1);          // round-to-nearest-even
  return (unsigned short)(b >> 16);
}
__device__ __forceinline__ float bflo(unsigned u) {   // low 16 bits -> float
  return __uint_as_float(u << 16);
}
__device__ __forceinline__ float bfhi(unsigned u) {   // high 16 bits -> float
  return __uint_as_float(u & 0xFFFF0000u);
}
__device__ __forceinline__ unsigned pack2(float a, float b) {
  return (unsigned)f2bf(a) | ((unsigned)f2bf(b) << 16);
}

// ---------- prep: cursor init (block 0) + weight split (1) + graph bounds (2) ----------
__global__ __launch_bounds__(256) void prep_kernel(
    int* __restrict__ gcur,
    const float* __restrict__ W1l, const float* __restrict__ W1r,
    short* __restrict__ wfrag, const int* __restrict__ batch,
    int* __restrict__ gs) {
  int b = blockIdx.x;
  if (b == 0) {                       // --- bucket cursors: base of each region ---
    for (int i = threadIdx.x; i < NB; i += 256) gcur[i] = i * CAP;
  } else if (b == 1) {                // --- weight split ---
    for (int i = threadIdx.x; i < DIN * DH; i += 256) {
      int k = i >> 6, n = i & 63;
      int kt = k >> 5, kin = k & 31;
      int lane = ((kin >> 3) << 4) | (n & 15);
      int j8 = kin & 7;
      int jt = n >> 4;
      float wl = W1l[i], wr = W1r[i];
      unsigned bl_ = __float_as_uint(wl);
      unsigned br_ = __float_as_uint(wr);
      short hl = (short)(bl_ >> 16);
      short hr = (short)(br_ >> 16);
      float rl = wl - __uint_as_float(bl_ & 0xFFFF0000u);
      float rr = wr - __uint_as_float(br_ & 0xFFFF0000u);
      short ll = (short)(__float_as_uint(rl) >> 16);
      short lr = (short)(__float_as_uint(rr) >> 16);
      int base0 = (((kt * 2 + 0) * 4 + jt) * 2) * 512 + lane * 8 + j8;
      int base1 = (((kt * 2 + 1) * 4 + jt) * 2) * 512 + lane * 8 + j8;
      wfrag[base0]       = hl;
      wfrag[base0 + 512] = ll;
      wfrag[base1]       = hr;
      wfrag[base1 + 512] = lr;
    }
  } else {                            // --- graph boundaries ---
    for (int g = threadIdx.x; g <= NG; g += 256) {
      if (g == NG) { gs[NG] = NN; continue; }
      int lo = 0, hi = NN;
      while (lo < hi) {
        int mid = (lo + hi) >> 1;
        if (batch[mid] < g) lo = mid + 1; else hi = mid;
      }
      gs[g] = lo;
    }
  }
}

// ---------- fused: slice-claim partA (blocks 0..249) + proj MFMA (250..1031) ----------
// partA: dst slice cached in LDS (single global dst pass); LDS hist -> 1 global
// atomic per (block,bucket) slice claim -> LDS-cursor scatter.
// proj: round-9/12 verified 2-tile 2-stage LDS form.
__global__ __launch_bounds__(256, 4) void proj_part_kernel(
    const int* __restrict__ src, const int* __restrict__ dst,
    int* __restrict__ gcur, int* __restrict__ part,
    const float* __restrict__ x, const short* __restrict__ wfrag,
    const float* __restrict__ b1, unsigned short* __restrict__ xlb,
    unsigned short* __restrict__ xrb) {
  __shared__ short sB[16384];   // 32 KB (partA aliases: dstL[EPB] + 3x int[NB])
  if (blockIdx.x < PARTB) {
    int* dstL  = (int*)sB;            // [EPB] 25.6 KB, 16B-aligned at offset 0
    int* hist  = dstL + EPB;          // [NB]
    int* base_ = hist + NB;           // [NB]
    int* lcur  = base_ + NB;          // [NB]  total 30,292 B <= 32 KB
    for (int i = threadIdx.x; i < NB; i += 256) hist[i] = 0;
    __syncthreads();
    int start = blockIdx.x * EPB;
    const int4* d4 = (const int4*)(dst + start);   // 16B-aligned
    const int4* s4 = (const int4*)(src + start);
    for (int i = threadIdx.x; i < EPB / 4; i += 256) {
      int4 d = d4[i];
      ((int4*)dstL)[i] = d;                        // cache dst slice in LDS
      atomicAdd(&hist[d.x >> 8], 1);
      atomicAdd(&hist[d.y >> 8], 1);
      atomicAdd(&hist[d.z >> 8], 1);
      atomicAdd(&hist[d.w >> 8], 1);
    }
    __syncthreads();
    for (int i = threadIdx.x; i < NB; i += 256) {
      base_[i] = atomicAdd(&gcur[i], hist[i]);     // 1 global atomic / bucket
      lcur[i] = 0;
    }
    __syncthreads();
    for (int i = threadIdx.x; i < EPB / 4; i += 256) {
      int4 d = ((const int4*)dstL)[i];             // dst from LDS
      int4 s = s4[i];
      int de[4] = {d.x, d.y, d.z, d.w};
      int se[4] = {s.x, s.y, s.z, s.w};
#pragma unroll
      for (int u = 0; u < 4; ++u) {
        int bkt = de[u] >> 8;
        int pos = base_[bkt] + atomicAdd(&lcur[bkt], 1);  // LDS atomic
        if (pos < (bkt + 1) * CAP)                        // overflow guard
          part[pos] = ((de[u] & 255) << 17) | se[u];
      }
    }
    return;
  }
  // --- proj: xl(bf16)=x@W1l, xr(bf16)=x@W1r+b1 (round-9/12 verified structure) ---
  int wave = threadIdx.x >> 6;
  int lane = threadIdx.x & 63;
  int m = lane & 15, q = lane >> 4;
  int tpair = (blockIdx.x - PARTB) * 4 + wave;
  int tile0 = tpair * 2, tile1 = tile0 + 1;
  bool act0 = tile0 < 6250;
  bool act1 = tile1 < 6250;
  int t0c = act0 ? tile0 : 6249;   // clamp: tail waves compute garbage, skip stores
  int t1c = act1 ? tile1 : 6249;

  int r0 = t0c * 16 + m;
  int r1 = t1c * 16 + m;
  const float4* xa = (const float4*)x + (size_t)r0 * 32 + q * 2;
  const float4* xb = (const float4*)x + (size_t)r1 * 32 + q * 2;

  floatx4 acc0[8], acc1[8];
#pragma unroll
  for (int a = 0; a < 8; ++a) {
    acc0[a] = (floatx4){0.f, 0.f, 0.f, 0.f};
    acc1[a] = (floatx4){0.f, 0.f, 0.f, 0.f};
  }

  const float4* wf4 = (const float4*)wfrag;
  float4* sB4 = (float4*)sB;

#pragma unroll 1              // keep rolled: bounds VGPR, prevents load hoisting
  for (int stage = 0; stage < 2; ++stage) {
    if (stage) __syncthreads();              // stage-0 reads done before overwrite
    for (int i = threadIdx.x; i < 2048; i += 256)
      sB4[i] = wf4[stage * 2048 + i];        // 32 KB of wfrag (L2-resident)
    __syncthreads();

#pragma unroll
    for (int kk = 0; kk < 2; ++kk) {
      int kt = stage * 2 + kk;
      float4 p0 = xa[kt * 8];
      float4 p1 = xa[kt * 8 + 1];
      float4 p2 = xb[kt * 8];
      float4 p3 = xb[kt * 8 + 1];
      float af0[8] = {p0.x, p0.y, p0.z, p0.w, p1.x, p1.y, p1.z, p1.w};
      float af1[8] = {p2.x, p2.y, p2.z, p2.w, p3.x, p3.y, p3.z, p3.w};
      short8 ah0, al0, ah1, al1;
#pragma unroll
      for (int e = 0; e < 8; ++e) {
        unsigned b0 = __float_as_uint(af0[e]);
        ah0[e] = (short)(b0 >> 16);
        float lo0 = af0[e] - __uint_as_float(b0 & 0xFFFF0000u);
        al0[e] = (short)(__float_as_uint(lo0) >> 16);
        unsigned b1_ = __float_as_uint(af1[e]);
        ah1[e] = (short)(b1_ >> 16);
        float lo1 = af1[e] - __uint_as_float(b1_ & 0xFFFF0000u);
        al1[e] = (short)(__float_as_uint(lo1) >> 16);
      }
#pragma unroll
      for (int mat = 0; mat < 2; ++mat) {
#pragma unroll
        for (int jt = 0; jt < 4; ++jt) {
          int unit = ((kk * 2 + mat) * 4 + jt) * 2;   // local unit within stage
          short8 bh = *(const short8*)(sB + unit * 512 + lane * 8);
          short8 bl = *(const short8*)(sB + (unit + 1) * 512 + lane * 8);
          floatx4 c0 = acc0[mat * 4 + jt];
          c0 = __builtin_amdgcn_mfma_f32_16x16x32_bf16(ah0, bh, c0, 0, 0, 0);
          c0 = __builtin_amdgcn_mfma_f32_16x16x32_bf16(ah0, bl, c0, 0, 0, 0);
          c0 = __builtin_amdgcn_mfma_f32_16x16x32_bf16(al0, bh, c0, 0, 0, 0);
          acc0[mat * 4 + jt] = c0;
          floatx4 c1 = acc1[mat * 4 + jt];
          c1 = __builtin_amdgcn_mfma_f32_16x16x32_bf16(ah1, bh, c1, 0, 0, 0);
          c1 = __builtin_amdgcn_mfma_f32_16x16x32_bf16(ah1, bl, c1, 0, 0, 0);
          c1 = __builtin_amdgcn_mfma_f32_16x16x32_bf16(al1, bh, c1, 0, 0, 0);
          acc1[mat * 4 + jt] = c1;
        }
      }
    }
  }

#pragma unroll
  for (int jt = 0; jt < 4; ++jt) {
    int j = jt * 16 + m;
    float bj = b1[j];
    floatx4 cl0 = acc0[jt], cr0 = acc0[4 + jt];
    floatx4 cl1 = acc1[jt], cr1 = acc1[4 + jt];
    if (act0) {
#pragma unroll
      for (int r = 0; r < 4; ++r) {
        int n0 = tile0 * 16 + q * 4 + r;
        xlb[(size_t)n0 * DH + j] = f2bf(cl0[r]);
        xrb[(size_t)n0 * DH + j] = f2bf(cr0[r] + bj);
      }
    }
    if (act1) {
#pragma unroll
      for (int r = 0; r < 4; ++r) {
        int n1 = tile1 * 16 + q * 4 + r;
        xlb[(size_t)n1 * DH + j] = f2bf(cl1[r]);
        xrb[(size_t)n1 * DH + j] = f2bf(cr1[r] + bj);
      }
    }
  }
}

// ---------- fused CSR + layer-1 gather: one block per bucket, 1024 threads ----------
// (verified round 12: LDS-resident eidx slice, local row bounds, 8-deep gather)
__global__ __launch_bounds__(1024) void csr_gather1_kernel(
    const int* __restrict__ part, const int* __restrict__ gcur,
    int* __restrict__ row_start, int* __restrict__ row_end,
    int* __restrict__ eidx,
    const uint4* __restrict__ xlb4, const uint4* __restrict__ xrb4,
    uint4* __restrict__ hb4) {
  int b = blockIdx.x, t = threadIdx.x;
  int ebeg = b * CAP;
  int cnt_b = gcur[b] - ebeg; if (cnt_b > CAP) cnt_b = CAP;
  int nbase = b << 8;
  int nloc = NN - nbase; if (nloc > 256) nloc = 256;

  __shared__ int cntL[256];     // counts, then scatter cursor
  __shared__ int lsA[256];      // scan temp, then local row start
  __shared__ int leA[256];      // local row end
  __shared__ int eidxL[CAP];    // 20 KB LDS-resident eidx slice

  if (t < 256) cntL[t] = 0;
  __syncthreads();

  // --- histogram (int4 reads, 1024 threads) ---
  int nvec = cnt_b >> 2;
  const int4* p4 = (const int4*)(part + ebeg);     // ebeg = b*CAP, 16B-aligned
  for (int i = t; i < nvec; i += 1024) {
    int4 v = p4[i];
    atomicAdd(&cntL[v.x >> 17], 1);
    atomicAdd(&cntL[v.y >> 17], 1);
    atomicAdd(&cntL[v.z >> 17], 1);
    atomicAdd(&cntL[v.w >> 17], 1);
  }
  for (int e = (nvec << 2) + t; e < cnt_b; e += 1024)
    atomicAdd(&cntL[part[ebeg + e] >> 17], 1);
  __syncthreads();

  // --- exclusive scan over 256 node-counts (threads <256 active, all at barriers) ---
  int c = 0;
  if (t < 256) { c = cntL[t]; lsA[t] = c; }
  __syncthreads();
  for (int off = 1; off < 256; off <<= 1) {
    int v = 0;
    if (t < 256 && t >= off) v = lsA[t - off];
    __syncthreads();
    if (t < 256) lsA[t] += v;
    __syncthreads();
  }
  if (t < 256) {
    int excl = lsA[t] - c;
    lsA[t] = excl;
    leA[t] = excl + c;
    if (t < nloc) {                        // global bounds for gather2 only
      row_start[nbase + t] = ebeg + excl;
      row_end[nbase + t]   = ebeg + excl + c;
    }
    cntL[t] = excl;                        // reuse as scatter cursor
  }
  __syncthreads();

  // --- scatter: part -> LDS eidx (+ global eidx for gather2) ---
  for (int i = t; i < nvec; i += 1024) {
    int4 v = p4[i];
    int ve[4] = {v.x, v.y, v.z, v.w};
#pragma unroll
    for (int u = 0; u < 4; ++u) {
      int pos = atomicAdd(&cntL[ve[u] >> 17], 1);
      int s = ve[u] & 0x1FFFF;
      eidxL[pos] = s;
      eidx[ebeg + pos] = s;
    }
  }
  for (int e = (nvec << 2) + t; e < cnt_b; e += 1024) {
    int v = part[ebeg + e];
    int pos = atomicAdd(&cntL[v >> 17], 1);
    int s = v & 0x1FFFF;
    eidxL[pos] = s;
    eidx[ebeg + pos] = s;
  }
  __syncthreads();

  // --- layer-1 gather for own bucket: 8 lanes/node, 128 nodes/pass, 2 passes ---
  int fl = t & 7;
  for (int pass = 0; pass < 2; ++pass) {
    int nl = (t >> 3) + (pass << 7);
    if (nl >= nloc) continue;              // no barriers below — safe
    int rs = lsA[nl], re = leA[nl];
    float a0 = 0.f, a1 = 0.f, a2 = 0.f, a3 = 0.f;
    float a4 = 0.f, a5 = 0.f, a6 = 0.f, a7 = 0.f;
    int k = rs;
    for (; k + 8 <= re; k += 8) {          // 8 uint4 loads in flight
      uint4 v[8];
#pragma unroll
      for (int u = 0; u < 8; ++u) v[u] = xlb4[(size_t)eidxL[k + u] * 8 + fl];
#pragma unroll
      for (int u = 0; u < 8; ++u) {
        a0 += bflo(v[u].x); a1 += bfhi(v[u].x);
        a2 += bflo(v[u].y); a3 += bfhi(v[u].y);
        a4 += bflo(v[u].z); a5 += bfhi(v[u].z);
        a6 += bflo(v[u].w); a7 += bfhi(v[u].w);
      }
    }
    for (; k + 2 <= re; k += 2) {
      uint4 v0 = xlb4[(size_t)eidxL[k] * 8 + fl];
      uint4 v1 = xlb4[(size_t)eidxL[k + 1] * 8 + fl];
      a0 += bflo(v0.x) + bflo(v1.x); a1 += bfhi(v0.x) + bfhi(v1.x);
      a2 += bflo(v0.y) + bflo(v1.y); a3 += bfhi(v0.y) + bfhi(v1.y);
      a4 += bflo(v0.z) + bflo(v1.z); a5 += bfhi(v0.z) + bfhi(v1.z);
      a6 += bflo(v0.w) + bflo(v1.w); a7 += bfhi(v0.w) + bfhi(v1.w);
    }
    if (k < re) {
      uint4 v = xlb4[(size_t)eidxL[k] * 8 + fl];
      a0 += bflo(v.x); a1 += bfhi(v.x);
      a2 += bflo(v.y); a3 += bfhi(v.y);
      a4 += bflo(v.z); a5 += bfhi(v.z);
      a6 += bflo(v.w); a7 += bfhi(v.w);
    }
    float inv = 1.0f / fmaxf((float)(re - rs), 1.0f);
    a0 *= inv; a1 *= inv; a2 *= inv; a3 *= inv;
    a4 *= inv; a5 *= inv; a6 *= inv; a7 *= inv;
    int node = nbase + nl;
    uint4 r = xrb4[(size_t)node * 8 + fl];       // + root, relu
    a0 = fmaxf(a0 + bflo(r.x), 0.f); a1 = fmaxf(a1 + bfhi(r.x), 0.f);
    a2 = fmaxf(a2 + bflo(r.y), 0.f); a3 = fmaxf(a3 + bfhi(r.y), 0.f);
    a4 = fmaxf(a4 + bflo(r.z), 0.f); a5 = fmaxf(a5 + bfhi(r.z), 0.f);
    a6 = fmaxf(a6 + bflo(r.w), 0.f); a7 = fmaxf(a7 + bfhi(r.w), 0.f);
    uint4 o;
    o.x = pack2(a0, a1);
    o.y = pack2(a2, a3);
    o.z = pack2(a4, a5);
    o.w = pack2(a6, a7);
    hb4[(size_t)node * 8 + fl] = o;
  }
}

// ---------- fused layer-2 gather + pool + final matmul: one block per graph ----------
// 8-deep load pipeline (matched to gather1's verified structure).
__global__ __launch_bounds__(1024) void gather2_pool_kernel(
    const uint4* __restrict__ feat4,          // hb rows (bf16, 8x uint4/node)
    const int* __restrict__ row_start, const int* __restrict__ row_end,
    const int* __restrict__ eidx,
    const int* __restrict__ gs, const float* __restrict__ W2l,
    const float* __restrict__ W2r, const float* __restrict__ b2,
    float* __restrict__ out) {
  int g = blockIdx.x;
  int start = gs[g], end = gs[g + 1];
  int slot = threadIdx.x >> 3;        // 0..127 node-slot
  int fl   = threadIdx.x & 7;         // 16B feature chunk (feats fl*8..fl*8+7)
  float sm[8], sh[8];
#pragma unroll
  for (int i = 0; i < 8; ++i) { sm[i] = 0.f; sh[i] = 0.f; }

  for (int n = start + slot; n < end; n += 128) {
    int rs = row_start[n], re = row_end[n];
    uint4 hv = feat4[(size_t)n * 8 + fl];       // root h (issued early)
    float a0 = 0.f, a1 = 0.f, a2 = 0.f, a3 = 0.f;
    float a4 = 0.f, a5 = 0.f, a6 = 0.f, a7 = 0.f;
    int k = rs;
    for (; k + 8 <= re; k += 8) {       // 8 uint4 loads in flight
      uint4 v[8];
#pragma unroll
      for (int u = 0; u < 8; ++u) v[u] = feat4[(size_t)eidx[k + u] * 8 + fl];
#pragma unroll
      for (int u = 0; u < 8; ++u) {
        a0 += bflo(v[u].x); a1 += bfhi(v[u].x);
        a2 += bflo(v[u].y); a3 += bfhi(v[u].y);
        a4 += bflo(v[u].z); a5 += bfhi(v[u].z);
        a6 += bflo(v[u].w); a7 += bfhi(v[u].w);
      }
    }
    for (; k + 2 <= re; k += 2) {
      uint4 v0 = feat4[(size_t)eidx[k] * 8 + fl];
      uint4 v1 = feat4[(size_t)eidx[k + 1] * 8 + fl];
      a0 += bflo(v0.x) + bflo(v1.x); a1 += bfhi(v0.x) + bfhi(v1.x);
      a2 += bflo(v0.y) + bflo(v1.y); a3 += bfhi(v0.y) + bfhi(v1.y);
      a4 += bflo(v0.z) + bflo(v1.z); a5 += bfhi(v0.z) + bfhi(v1.z);
      a6 += bflo(v0.w) + bflo(v1.w); a7 += bfhi(v0.w) + bfhi(v1.w);
    }
    if (k < re) {
      uint4 v = feat4[(size_t)eidx[k] * 8 + fl];
      a0 += bflo(v.x); a1 += bfhi(v.x);
      a2 += bflo(v.y); a3 += bfhi(v.y);
      a4 += bflo(v.z); a5 += bfhi(v.z);
      a6 += bflo(v.w); a7 += bfhi(v.w);
    }
    float inv = 1.0f / fmaxf((float)(re - rs), 1.0f);
    sm[0] += a0 * inv; sm[1] += a1 * inv; sm[2] += a2 * inv; sm[3] += a3 * inv;
    sm[4] += a4 * inv; sm[5] += a5 * inv; sm[6] += a6 * inv; sm[7] += a7 * inv;
    sh[0] += bflo(hv.x); sh[1] += bfhi(hv.x);
    sh[2] += bflo(hv.y); sh[3] += bfhi(hv.y);
    sh[4] += bflo(hv.z); sh[5] += bfhi(hv.z);
    sh[6] += bflo(hv.w); sh[7] += bfhi(hv.w);
  }

  // reduce the 8 node-slot groups inside each wave (lane bits [5:3])
#pragma unroll
  for (int off = 8; off <= 32; off <<= 1) {
#pragma unroll
    for (int i = 0; i < 8; ++i) {
      sm[i] += __shfl_xor(sm[i], off);
      sh[i] += __shfl_xor(sh[i], off);
    }
  }

  __shared__ float redm[16][DH];
  __shared__ float redh[16][DH];
  int wv = threadIdx.x >> 6;
  int lane = threadIdx.x & 63;
  if (lane < 8) {
#pragma unroll
    for (int i = 0; i < 8; ++i) {
      redm[wv][lane * 8 + i] = sm[i];
      redh[wv][lane * 8 + i] = sh[i];
    }
  }
  __syncthreads();
  __shared__ float msL[DH], hsL[DH];
  if (threadIdx.x < DH) {
    float a = 0.f, b = 0.f;
#pragma unroll
    for (int w = 0; w < 16; ++w) { a += redm[w][threadIdx.x]; b += redh[w][threadIdx.x]; }
    msL[threadIdx.x] = a; hsL[threadIdx.x] = b;
  }
  __syncthreads();
  int j = threadIdx.x;
  if (j < DOUT) {
    float n_ = (float)(end - start);
    float acc = 0.f;
#pragma unroll 8
    for (int k = 0; k < DH; ++k)
      acc += msL[k] * W2l[k * DOUT + j] + hsL[k] * W2r[k * DOUT + j];
    out[g * DOUT + j] = (acc + n_ * b2[j]) / fmaxf(n_, 1.0f);
  }
}

extern "C" void kernel_launch(void* const* d_in, const int* in_sizes, int n_in,
                              void* d_out, int out_size, void* d_ws, size_t ws_size,
                              hipStream_t stream) {
  (void)in_sizes; (void)n_in; (void)out_size; (void)ws_size;
  const float* x   = (const float*)d_in[0];
  const float* W1l = (const float*)d_in[1];
  const float* W1r = (const float*)d_in[2];
  const float* b1  = (const float*)d_in[3];
  const float* W2l = (const float*)d_in[4];
  const float* W2r = (const float*)d_in[5];
  const float* b2  = (const float*)d_in[6];
  const int*   ei  = (const int*)d_in[7];
  const int*   batch = (const int*)d_in[8];
  const int* src = ei;            // edge_index[0, :]
  const int* dst = ei + NE;       // edge_index[1, :]
  float* out = (float*)d_out;

  char* ws = (char*)d_ws;
  unsigned short* xlb = (unsigned short*)(ws);            // 12,800,000 B
  unsigned short* hb  = (unsigned short*)(ws + 12800000); // 12,800,000 B
  unsigned short* xrb = (unsigned short*)(ws + 38400000); // 12,800,000 B
  int*  part      = (int*)(ws + 51200000);           //  8,007,680 B (NB*CAP*4)
  int*  gcur      = (int*)(ws + 59300000);           //      1,564 B
  int*  eidx      = (int*)(ws + 60000000);           //  8,007,680 B (padded)
  int*  row_start = (int*)(ws + 83200000);           //    400,000 B
  int*   gs       = (int*)(ws + 83600128);           //      2,052 B
  short* wfrag    = (short*)(ws + 83900032);         //     65,536 B
  int*  row_end   = (int*)(ws + 84000000);           //    400,000 B

  // prep: bucket cursors + weight split + graph bounds (3 tiny block roles)
  prep_kernel<<<3, 256, 0, stream>>>(gcur, W1l, W1r, wfrag, batch, gs);

  // slice-claim partA (LDS-cached dst, single global dst pass) fused with proj
  proj_part_kernel<<<PARTB + 782, 256, 0, stream>>>(src, dst, gcur, part,
                                                    x, wfrag, b1, xlb, xrb);

  // fused per-bucket CSR build + layer-1 gather (LDS-resident eidx)
  csr_gather1_kernel<<<NB, 1024, 0, stream>>>(
      part, gcur, row_start, row_end, eidx,
      (const uint4*)xlb, (const uint4*)xrb, (uint4*)hb);

  // layer 2 aggregation fused with pool + final matmul (one block per graph)
  gather2_pool_kernel<<<NG, 1024, 0, stream>>>(
      (const uint4*)hb, row_start, row_end, eidx, gs, W2l, W2r, b2, out);
}

// Round 14
// 219.222 us; speedup vs baseline: 1.0284x; 1.0284x over previous
//
#include <hip/hip_runtime.h>

#define NN   100000
#define NE   1600000
#define DIN  128
#define DH   64
#define DOUT 128
#define NG   512

#define NB    391    // dst buckets of 256 nodes: ceil(NN/256)
#define PARTB 250    // partA blocks
#define EPB   6400   // edges per partA block (= NE/250; 16B-aligned slices)
#define CAP   5120   // padded bucket capacity (verified sufficient rounds 8-13)

typedef short short8 __attribute__((ext_vector_type(8)));
typedef float floatx4 __attribute__((ext_vector_type(4)));

__device__ __forceinline__ unsigned short f2bf(float f) {
  unsigned b = __float_as_uint(f);
  b += 0x7FFF + ((b >> 16) & 1);          // round-to-nearest-even
  return (unsigned short)(b >> 16);
}
__device__ __forceinline__ float bflo(unsigned u) {   // low 16 bits -> float
  return __uint_as_float(u << 16);
}
__device__ __forceinline__ float bfhi(unsigned u) {   // high 16 bits -> float
  return __uint_as_float(u & 0xFFFF0000u);
}
__device__ __forceinline__ unsigned pack2(float a, float b) {
  return (unsigned)f2bf(a) | ((unsigned)f2bf(b) << 16);
}

// ---------- prep: cursor init (block 0) + weight split (1) + graph bounds (2) ----------
__global__ __launch_bounds__(256) void prep_kernel(
    int* __restrict__ gcur,
    const float* __restrict__ W1l, const float* __restrict__ W1r,
    short* __restrict__ wfrag, const int* __restrict__ batch,
    int* __restrict__ gs) {
  int b = blockIdx.x;
  if (b == 0) {                       // --- bucket cursors: base of each region ---
    for (int i = threadIdx.x; i < NB; i += 256) gcur[i] = i * CAP;
  } else if (b == 1) {                // --- weight split ---
    for (int i = threadIdx.x; i < DIN * DH; i += 256) {
      int k = i >> 6, n = i & 63;
      int kt = k >> 5, kin = k & 31;
      int lane = ((kin >> 3) << 4) | (n & 15);
      int j8 = kin & 7;
      int jt = n >> 4;
      float wl = W1l[i], wr = W1r[i];
      unsigned bl_ = __float_as_uint(wl);
      unsigned br_ = __float_as_uint(wr);
      short hl = (short)(bl_ >> 16);
      short hr = (short)(br_ >> 16);
      float rl = wl - __uint_as_float(bl_ & 0xFFFF0000u);
      float rr = wr - __uint_as_float(br_ & 0xFFFF0000u);
      short ll = (short)(__float_as_uint(rl) >> 16);
      short lr = (short)(__float_as_uint(rr) >> 16);
      int base0 = (((kt * 2 + 0) * 4 + jt) * 2) * 512 + lane * 8 + j8;
      int base1 = (((kt * 2 + 1) * 4 + jt) * 2) * 512 + lane * 8 + j8;
      wfrag[base0]       = hl;
      wfrag[base0 + 512] = ll;
      wfrag[base1]       = hr;
      wfrag[base1 + 512] = lr;
    }
  } else {                            // --- graph boundaries ---
    for (int g = threadIdx.x; g <= NG; g += 256) {
      if (g == NG) { gs[NG] = NN; continue; }
      int lo = 0, hi = NN;
      while (lo < hi) {
        int mid = (lo + hi) >> 1;
        if (batch[mid] < g) lo = mid + 1; else hi = mid;
      }
      gs[g] = lo;
    }
  }
}

// ---------- fused: slice-claim partA (blocks 0..249) + proj MFMA (250..1031) ----------
// partA: dst slice cached in LDS (single global dst pass); LDS hist -> 1 global
// atomic per (block,bucket) slice claim -> LDS-cursor scatter.
// proj: 2-tile 2-stage LDS staging + NEW coalesced epilogue (LDS transpose,
// uint4 stores) — fixes the 1.6-2x WRITE_SIZE inflation from 2B scalar stores.
__global__ __launch_bounds__(256, 4) void proj_part_kernel(
    const int* __restrict__ src, const int* __restrict__ dst,
    int* __restrict__ gcur, int* __restrict__ part,
    const float* __restrict__ x, const short* __restrict__ wfrag,
    const float* __restrict__ b1, unsigned short* __restrict__ xlb,
    unsigned short* __restrict__ xrb) {
  __shared__ __align__(16) short sB[16384];   // 32 KB, multi-role
  if (blockIdx.x < PARTB) {
    int* dstL  = (int*)sB;            // [EPB] 25.6 KB, 16B-aligned at offset 0
    int* hist  = dstL + EPB;          // [NB]
    int* base_ = hist + NB;           // [NB]
    int* lcur  = base_ + NB;          // [NB]  total 30,292 B <= 32 KB
    for (int i = threadIdx.x; i < NB; i += 256) hist[i] = 0;
    __syncthreads();
    int start = blockIdx.x * EPB;
    const int4* d4 = (const int4*)(dst + start);   // 16B-aligned
    const int4* s4 = (const int4*)(src + start);
    for (int i = threadIdx.x; i < EPB / 4; i += 256) {
      int4 d = d4[i];
      ((int4*)dstL)[i] = d;                        // cache dst slice in LDS
      atomicAdd(&hist[d.x >> 8], 1);
      atomicAdd(&hist[d.y >> 8], 1);
      atomicAdd(&hist[d.z >> 8], 1);
      atomicAdd(&hist[d.w >> 8], 1);
    }
    __syncthreads();
    for (int i = threadIdx.x; i < NB; i += 256) {
      base_[i] = atomicAdd(&gcur[i], hist[i]);     // 1 global atomic / bucket
      lcur[i] = 0;
    }
    __syncthreads();
    for (int i = threadIdx.x; i < EPB / 4; i += 256) {
      int4 d = ((const int4*)dstL)[i];             // dst from LDS
      int4 s = s4[i];
      int de[4] = {d.x, d.y, d.z, d.w};
      int se[4] = {s.x, s.y, s.z, s.w};
#pragma unroll
      for (int u = 0; u < 4; ++u) {
        int bkt = de[u] >> 8;
        int pos = base_[bkt] + atomicAdd(&lcur[bkt], 1);  // LDS atomic
        if (pos < (bkt + 1) * CAP)                        // overflow guard
          part[pos] = ((de[u] & 255) << 17) | se[u];
      }
    }
    return;
  }
  // --- proj: xl(bf16)=x@W1l, xr(bf16)=x@W1r+b1 ---
  int wave = threadIdx.x >> 6;
  int lane = threadIdx.x & 63;
  int m = lane & 15, q = lane >> 4;
  int tpair = (blockIdx.x - PARTB) * 4 + wave;
  int tile0 = tpair * 2, tile1 = tile0 + 1;
  bool act0 = tile0 < 6250;
  bool act1 = tile1 < 6250;
  int t0c = act0 ? tile0 : 6249;   // clamp: tail waves compute garbage, skip stores
  int t1c = act1 ? tile1 : 6249;

  int r0 = t0c * 16 + m;
  int r1 = t1c * 16 + m;
  const float4* xa = (const float4*)x + (size_t)r0 * 32 + q * 2;
  const float4* xb = (const float4*)x + (size_t)r1 * 32 + q * 2;

  floatx4 acc0[8], acc1[8];
#pragma unroll
  for (int a = 0; a < 8; ++a) {
    acc0[a] = (floatx4){0.f, 0.f, 0.f, 0.f};
    acc1[a] = (floatx4){0.f, 0.f, 0.f, 0.f};
  }

  const float4* wf4 = (const float4*)wfrag;
  float4* sB4 = (float4*)sB;

#pragma unroll 1              // keep rolled: bounds VGPR, prevents load hoisting
  for (int stage = 0; stage < 2; ++stage) {
    if (stage) __syncthreads();              // stage-0 reads done before overwrite
    for (int i = threadIdx.x; i < 2048; i += 256)
      sB4[i] = wf4[stage * 2048 + i];        // 32 KB of wfrag (L2-resident)
    __syncthreads();

#pragma unroll
    for (int kk = 0; kk < 2; ++kk) {
      int kt = stage * 2 + kk;
      float4 p0 = xa[kt * 8];
      float4 p1 = xa[kt * 8 + 1];
      float4 p2 = xb[kt * 8];
      float4 p3 = xb[kt * 8 + 1];
      float af0[8] = {p0.x, p0.y, p0.z, p0.w, p1.x, p1.y, p1.z, p1.w};
      float af1[8] = {p2.x, p2.y, p2.z, p2.w, p3.x, p3.y, p3.z, p3.w};
      short8 ah0, al0, ah1, al1;
#pragma unroll
      for (int e = 0; e < 8; ++e) {
        unsigned b0 = __float_as_uint(af0[e]);
        ah0[e] = (short)(b0 >> 16);
        float lo0 = af0[e] - __uint_as_float(b0 & 0xFFFF0000u);
        al0[e] = (short)(__float_as_uint(lo0) >> 16);
        unsigned b1_ = __float_as_uint(af1[e]);
        ah1[e] = (short)(b1_ >> 16);
        float lo1 = af1[e] - __uint_as_float(b1_ & 0xFFFF0000u);
        al1[e] = (short)(__float_as_uint(lo1) >> 16);
      }
#pragma unroll
      for (int mat = 0; mat < 2; ++mat) {
#pragma unroll
        for (int jt = 0; jt < 4; ++jt) {
          int unit = ((kk * 2 + mat) * 4 + jt) * 2;   // local unit within stage
          short8 bh = *(const short8*)(sB + unit * 512 + lane * 8);
          short8 bl = *(const short8*)(sB + (unit + 1) * 512 + lane * 8);
          floatx4 c0 = acc0[mat * 4 + jt];
          c0 = __builtin_amdgcn_mfma_f32_16x16x32_bf16(ah0, bh, c0, 0, 0, 0);
          c0 = __builtin_amdgcn_mfma_f32_16x16x32_bf16(ah0, bl, c0, 0, 0, 0);
          c0 = __builtin_amdgcn_mfma_f32_16x16x32_bf16(al0, bh, c0, 0, 0, 0);
          acc0[mat * 4 + jt] = c0;
          floatx4 c1 = acc1[mat * 4 + jt];
          c1 = __builtin_amdgcn_mfma_f32_16x16x32_bf16(ah1, bh, c1, 0, 0, 0);
          c1 = __builtin_amdgcn_mfma_f32_16x16x32_bf16(ah1, bl, c1, 0, 0, 0);
          c1 = __builtin_amdgcn_mfma_f32_16x16x32_bf16(al1, bh, c1, 0, 0, 0);
          acc1[mat * 4 + jt] = c1;
        }
      }
    }
  }

  // --- coalesced epilogue: pack acc -> LDS (per-wave 8KB), store uint4 ---
  __syncthreads();                  // all staging reads done; sB reusable
  short* pk = sB + wave * 4096;     // [4 combos][16 nodes][64 j] bf16
#pragma unroll
  for (int jt = 0; jt < 4; ++jt) {
    int j = jt * 16 + m;
    int jc = j >> 3, jl = j & 7;
    float bj = b1[j];
#pragma unroll
    for (int r = 0; r < 4; ++r) {
      int node = q * 4 + r;
      int off = node * 64 + ((jc ^ (node & 7)) << 3) + jl;   // XOR-swizzled jc
      pk[off]        = (short)f2bf(acc0[jt][r]);
      pk[1024 + off] = (short)f2bf(acc0[4 + jt][r] + bj);
      pk[2048 + off] = (short)f2bf(acc1[jt][r]);
      pk[3072 + off] = (short)f2bf(acc1[4 + jt][r] + bj);
    }
  }
  // same-wave ds_write -> ds_read: compiler inserts lgkmcnt wait
  const uint4* pk4 = (const uint4*)pk;
  uint4* glb = (uint4*)xlb;
  uint4* grb = (uint4*)xrb;
#pragma unroll
  for (int c = 0; c < 2; ++c) {
    int chunk = lane + (c << 6);          // 0..127
    int nodeL = chunk >> 3, jc = chunk & 7;
    int li = nodeL * 8 + (jc ^ (nodeL & 7));
    if (act0) {
      size_t o0 = (size_t)(tile0 * 16 + nodeL) * 8 + jc;
      glb[o0] = pk4[li];
      grb[o0] = pk4[128 + li];
    }
    if (act1) {
      size_t o1 = (size_t)(tile1 * 16 + nodeL) * 8 + jc;
      glb[o1] = pk4[256 + li];
      grb[o1] = pk4[384 + li];
    }
  }
}

// ---------- fused CSR + layer-1 gather: one block per bucket, 1024 threads ----------
// (verified round 12: LDS-resident eidx slice, local row bounds, 8-deep gather)
__global__ __launch_bounds__(1024) void csr_gather1_kernel(
    const int* __restrict__ part, const int* __restrict__ gcur,
    int* __restrict__ row_start, int* __restrict__ row_end,
    int* __restrict__ eidx,
    const uint4* __restrict__ xlb4, const uint4* __restrict__ xrb4,
    uint4* __restrict__ hb4) {
  int b = blockIdx.x, t = threadIdx.x;
  int ebeg = b * CAP;
  int cnt_b = gcur[b] - ebeg; if (cnt_b > CAP) cnt_b = CAP;
  int nbase = b << 8;
  int nloc = NN - nbase; if (nloc > 256) nloc = 256;

  __shared__ int cntL[256];     // counts, then scatter cursor
  __shared__ int lsA[256];      // scan temp, then local row start
  __shared__ int leA[256];      // local row end
  __shared__ int eidxL[CAP];    // 20 KB LDS-resident eidx slice

  if (t < 256) cntL[t] = 0;
  __syncthreads();

  // --- histogram (int4 reads, 1024 threads) ---
  int nvec = cnt_b >> 2;
  const int4* p4 = (const int4*)(part + ebeg);     // ebeg = b*CAP, 16B-aligned
  for (int i = t; i < nvec; i += 1024) {
    int4 v = p4[i];
    atomicAdd(&cntL[v.x >> 17], 1);
    atomicAdd(&cntL[v.y >> 17], 1);
    atomicAdd(&cntL[v.z >> 17], 1);
    atomicAdd(&cntL[v.w >> 17], 1);
  }
  for (int e = (nvec << 2) + t; e < cnt_b; e += 1024)
    atomicAdd(&cntL[part[ebeg + e] >> 17], 1);
  __syncthreads();

  // --- exclusive scan over 256 node-counts (threads <256 active, all at barriers) ---
  int c = 0;
  if (t < 256) { c = cntL[t]; lsA[t] = c; }
  __syncthreads();
  for (int off = 1; off < 256; off <<= 1) {
    int v = 0;
    if (t < 256 && t >= off) v = lsA[t - off];
    __syncthreads();
    if (t < 256) lsA[t] += v;
    __syncthreads();
  }
  if (t < 256) {
    int excl = lsA[t] - c;
    lsA[t] = excl;
    leA[t] = excl + c;
    if (t < nloc) {                        // global bounds for gather2 only
      row_start[nbase + t] = ebeg + excl;
      row_end[nbase + t]   = ebeg + excl + c;
    }
    cntL[t] = excl;                        // reuse as scatter cursor
  }
  __syncthreads();

  // --- scatter: part -> LDS eidx (+ global eidx for gather2) ---
  for (int i = t; i < nvec; i += 1024) {
    int4 v = p4[i];
    int ve[4] = {v.x, v.y, v.z, v.w};
#pragma unroll
    for (int u = 0; u < 4; ++u) {
      int pos = atomicAdd(&cntL[ve[u] >> 17], 1);
      int s = ve[u] & 0x1FFFF;
      eidxL[pos] = s;
      eidx[ebeg + pos] = s;
    }
  }
  for (int e = (nvec << 2) + t; e < cnt_b; e += 1024) {
    int v = part[ebeg + e];
    int pos = atomicAdd(&cntL[v >> 17], 1);
    int s = v & 0x1FFFF;
    eidxL[pos] = s;
    eidx[ebeg + pos] = s;
  }
  __syncthreads();

  // --- layer-1 gather for own bucket: 8 lanes/node, 128 nodes/pass, 2 passes ---
  int fl = t & 7;
  for (int pass = 0; pass < 2; ++pass) {
    int nl = (t >> 3) + (pass << 7);
    if (nl >= nloc) continue;              // no barriers below — safe
    int rs = lsA[nl], re = leA[nl];
    float a0 = 0.f, a1 = 0.f, a2 = 0.f, a3 = 0.f;
    float a4 = 0.f, a5 = 0.f, a6 = 0.f, a7 = 0.f;
    int k = rs;
    for (; k + 8 <= re; k += 8) {          // 8 uint4 loads in flight
      uint4 v[8];
#pragma unroll
      for (int u = 0; u < 8; ++u) v[u] = xlb4[(size_t)eidxL[k + u] * 8 + fl];
#pragma unroll
      for (int u = 0; u < 8; ++u) {
        a0 += bflo(v[u].x); a1 += bfhi(v[u].x);
        a2 += bflo(v[u].y); a3 += bfhi(v[u].y);
        a4 += bflo(v[u].z); a5 += bfhi(v[u].z);
        a6 += bflo(v[u].w); a7 += bfhi(v[u].w);
      }
    }
    for (; k + 2 <= re; k += 2) {
      uint4 v0 = xlb4[(size_t)eidxL[k] * 8 + fl];
      uint4 v1 = xlb4[(size_t)eidxL[k + 1] * 8 + fl];
      a0 += bflo(v0.x) + bflo(v1.x); a1 += bfhi(v0.x) + bfhi(v1.x);
      a2 += bflo(v0.y) + bflo(v1.y); a3 += bfhi(v0.y) + bfhi(v1.y);
      a4 += bflo(v0.z) + bflo(v1.z); a5 += bfhi(v0.z) + bfhi(v1.z);
      a6 += bflo(v0.w) + bflo(v1.w); a7 += bfhi(v0.w) + bfhi(v1.w);
    }
    if (k < re) {
      uint4 v = xlb4[(size_t)eidxL[k] * 8 + fl];
      a0 += bflo(v.x); a1 += bfhi(v.x);
      a2 += bflo(v.y); a3 += bfhi(v.y);
      a4 += bflo(v.z); a5 += bfhi(v.z);
      a6 += bflo(v.w); a7 += bfhi(v.w);
    }
    float inv = 1.0f / fmaxf((float)(re - rs), 1.0f);
    a0 *= inv; a1 *= inv; a2 *= inv; a3 *= inv;
    a4 *= inv; a5 *= inv; a6 *= inv; a7 *= inv;
    int node = nbase + nl;
    uint4 r = xrb4[(size_t)node * 8 + fl];       // + root, relu
    a0 = fmaxf(a0 + bflo(r.x), 0.f); a1 = fmaxf(a1 + bfhi(r.x), 0.f);
    a2 = fmaxf(a2 + bflo(r.y), 0.f); a3 = fmaxf(a3 + bfhi(r.y), 0.f);
    a4 = fmaxf(a4 + bflo(r.z), 0.f); a5 = fmaxf(a5 + bfhi(r.z), 0.f);
    a6 = fmaxf(a6 + bflo(r.w), 0.f); a7 = fmaxf(a7 + bfhi(r.w), 0.f);
    uint4 o;
    o.x = pack2(a0, a1);
    o.y = pack2(a2, a3);
    o.z = pack2(a4, a5);
    o.w = pack2(a6, a7);
    hb4[(size_t)node * 8 + fl] = o;
  }
}

// ---------- fused layer-2 gather + pool + final matmul: one block per graph ----------
// 8-deep load pipeline (matched to gather1's verified structure).
__global__ __launch_bounds__(1024) void gather2_pool_kernel(
    const uint4* __restrict__ feat4,          // hb rows (bf16, 8x uint4/node)
    const int* __restrict__ row_start, const int* __restrict__ row_end,
    const int* __restrict__ eidx,
    const int* __restrict__ gs, const float* __restrict__ W2l,
    const float* __restrict__ W2r, const float* __restrict__ b2,
    float* __restrict__ out) {
  int g = blockIdx.x;
  int start = gs[g], end = gs[g + 1];
  int slot = threadIdx.x >> 3;        // 0..127 node-slot
  int fl   = threadIdx.x & 7;         // 16B feature chunk (feats fl*8..fl*8+7)
  float sm[8], sh[8];
#pragma unroll
  for (int i = 0; i < 8; ++i) { sm[i] = 0.f; sh[i] = 0.f; }

  for (int n = start + slot; n < end; n += 128) {
    int rs = row_start[n], re = row_end[n];
    uint4 hv = feat4[(size_t)n * 8 + fl];       // root h (issued early)
    float a0 = 0.f, a1 = 0.f, a2 = 0.f, a3 = 0.f;
    float a4 = 0.f, a5 = 0.f, a6 = 0.f, a7 = 0.f;
    int k = rs;
    for (; k + 8 <= re; k += 8) {       // 8 uint4 loads in flight
      uint4 v[8];
#pragma unroll
      for (int u = 0; u < 8; ++u) v[u] = feat4[(size_t)eidx[k + u] * 8 + fl];
#pragma unroll
      for (int u = 0; u < 8; ++u) {
        a0 += bflo(v[u].x); a1 += bfhi(v[u].x);
        a2 += bflo(v[u].y); a3 += bfhi(v[u].y);
        a4 += bflo(v[u].z); a5 += bfhi(v[u].z);
        a6 += bflo(v[u].w); a7 += bfhi(v[u].w);
      }
    }
    for (; k + 2 <= re; k += 2) {
      uint4 v0 = feat4[(size_t)eidx[k] * 8 + fl];
      uint4 v1 = feat4[(size_t)eidx[k + 1] * 8 + fl];
      a0 += bflo(v0.x) + bflo(v1.x); a1 += bfhi(v0.x) + bfhi(v1.x);
      a2 += bflo(v0.y) + bflo(v1.y); a3 += bfhi(v0.y) + bfhi(v1.y);
      a4 += bflo(v0.z) + bflo(v1.z); a5 += bfhi(v0.z) + bfhi(v1.z);
      a6 += bflo(v0.w) + bflo(v1.w); a7 += bfhi(v0.w) + bfhi(v1.w);
    }
    if (k < re) {
      uint4 v = feat4[(size_t)eidx[k] * 8 + fl];
      a0 += bflo(v.x); a1 += bfhi(v.x);
      a2 += bflo(v.y); a3 += bfhi(v.y);
      a4 += bflo(v.z); a5 += bfhi(v.z);
      a6 += bflo(v.w); a7 += bfhi(v.w);
    }
    float inv = 1.0f / fmaxf((float)(re - rs), 1.0f);
    sm[0] += a0 * inv; sm[1] += a1 * inv; sm[2] += a2 * inv; sm[3] += a3 * inv;
    sm[4] += a4 * inv; sm[5] += a5 * inv; sm[6] += a6 * inv; sm[7] += a7 * inv;
    sh[0] += bflo(hv.x); sh[1] += bfhi(hv.x);
    sh[2] += bflo(hv.y); sh[3] += bfhi(hv.y);
    sh[4] += bflo(hv.z); sh[5] += bfhi(hv.z);
    sh[6] += bflo(hv.w); sh[7] += bfhi(hv.w);
  }

  // reduce the 8 node-slot groups inside each wave (lane bits [5:3])
#pragma unroll
  for (int off = 8; off <= 32; off <<= 1) {
#pragma unroll
    for (int i = 0; i < 8; ++i) {
      sm[i] += __shfl_xor(sm[i], off);
      sh[i] += __shfl_xor(sh[i], off);
    }
  }

  __shared__ float redm[16][DH];
  __shared__ float redh[16][DH];
  int wv = threadIdx.x >> 6;
  int lane = threadIdx.x & 63;
  if (lane < 8) {
#pragma unroll
    for (int i = 0; i < 8; ++i) {
      redm[wv][lane * 8 + i] = sm[i];
      redh[wv][lane * 8 + i] = sh[i];
    }
  }
  __syncthreads();
  __shared__ float msL[DH], hsL[DH];
  if (threadIdx.x < DH) {
    float a = 0.f, b = 0.f;
#pragma unroll
    for (int w = 0; w < 16; ++w) { a += redm[w][threadIdx.x]; b += redh[w][threadIdx.x]; }
    msL[threadIdx.x] = a; hsL[threadIdx.x] = b;
  }
  __syncthreads();
  int j = threadIdx.x;
  if (j < DOUT) {
    float n_ = (float)(end - start);
    float acc = 0.f;
#pragma unroll 8
    for (int k = 0; k < DH; ++k)
      acc += msL[k] * W2l[k * DOUT + j] + hsL[k] * W2r[k * DOUT + j];
    out[g * DOUT + j] = (acc + n_ * b2[j]) / fmaxf(n_, 1.0f);
  }
}

extern "C" void kernel_launch(void* const* d_in, const int* in_sizes, int n_in,
                              void* d_out, int out_size, void* d_ws, size_t ws_size,
                              hipStream_t stream) {
  (void)in_sizes; (void)n_in; (void)out_size; (void)ws_size;
  const float* x   = (const float*)d_in[0];
  const float* W1l = (const float*)d_in[1];
  const float* W1r = (const float*)d_in[2];
  const float* b1  = (const float*)d_in[3];
  const float* W2l = (const float*)d_in[4];
  const float* W2r = (const float*)d_in[5];
  const float* b2  = (const float*)d_in[6];
  const int*   ei  = (const int*)d_in[7];
  const int*   batch = (const int*)d_in[8];
  const int* src = ei;            // edge_index[0, :]
  const int* dst = ei + NE;       // edge_index[1, :]
  float* out = (float*)d_out;

  char* ws = (char*)d_ws;
  unsigned short* xlb = (unsigned short*)(ws);            // 12,800,000 B
  unsigned short* hb  = (unsigned short*)(ws + 12800000); // 12,800,000 B
  unsigned short* xrb = (unsigned short*)(ws + 38400000); // 12,800,000 B
  int*  part      = (int*)(ws + 51200000);           //  8,007,680 B (NB*CAP*4)
  int*  gcur      = (int*)(ws + 59300000);           //      1,564 B
  int*  eidx      = (int*)(ws + 60000000);           //  8,007,680 B (padded)
  int*  row_start = (int*)(ws + 83200000);           //    400,000 B
  int*   gs       = (int*)(ws + 83600128);           //      2,052 B
  short* wfrag    = (short*)(ws + 83900032);         //     65,536 B
  int*  row_end   = (int*)(ws + 84000000);           //    400,000 B

  // prep: bucket cursors + weight split + graph bounds (3 tiny block roles)
  prep_kernel<<<3, 256, 0, stream>>>(gcur, W1l, W1r, wfrag, batch, gs);

  // slice-claim partA (LDS-cached dst) fused with proj (coalesced epilogue)
  proj_part_kernel<<<PARTB + 782, 256, 0, stream>>>(src, dst, gcur, part,
                                                    x, wfrag, b1, xlb, xrb);

  // fused per-bucket CSR build + layer-1 gather (LDS-resident eidx)
  csr_gather1_kernel<<<NB, 1024, 0, stream>>>(
      part, gcur, row_start, row_end, eidx,
      (const uint4*)xlb, (const uint4*)xrb, (uint4*)hb);

  // layer 2 aggregation fused with pool + final matmul (one block per graph)
  gather2_pool_kernel<<<NG, 1024, 0, stream>>>(
      (const uint4*)hb, row_start, row_end, eidx, gs, W2l, W2r, b2, out);
}